// Round 2
// baseline (248.715 us; speedup 1.0000x reference)
//
#include <hip/hip_runtime.h>
#include <hip/hip_cooperative_groups.h>
#include <cstdint>

namespace cg = cooperative_groups;

#define N_NODES 4096
#define N_EDGES 131072
// out = N*(N-1)/2 = 8386560 floats = 2096640 float4
#define OUT_ELEMS (N_NODES * (N_NODES - 1) / 2)
#define OUT_QUADS (OUT_ELEMS / 4)
// one bit per output element; 8386560/32 = 262080 words, padded to 262144 (1 MiB) per map
#define BM_WORDS_PAD 262144
#define NBLK 1024
#define NTHR 256
#define NTOT (NBLK * NTHR)  // 262144 == 2*N_EDGES exactly

// Exact reference arithmetic: v(bs,bt) = Qt[0][1][bt] * Qt[t-1][bs][1] / Qt[t][bs][bt]
__device__ __forceinline__ void compute_vals(const float* __restrict__ Qt,
                                             const int* __restrict__ t_ptr,
                                             float* vals) {
    const int t = t_ptr[0];
    const float l0 = Qt[2], l1 = Qt[3];                              // Qt[0][1][bt]
    const float p0 = Qt[(t - 1) * 4 + 1], p1 = Qt[(t - 1) * 4 + 3]; // Qt[t-1][bs][1]
    const float e00 = Qt[t * 4 + 0], e01 = Qt[t * 4 + 1];
    const float e10 = Qt[t * 4 + 2], e11 = Qt[t * 4 + 3];
    vals[0] = l0 * p0 / e00;  // bs=0, bt=0
    vals[1] = l1 * p0 / e01;  // bs=0, bt=1
    vals[2] = l0 * p1 / e10;  // bs=1, bt=0
    vals[3] = l1 * p1 / e11;  // bs=1, bt=1
}

// triangle-linear index for i<j (row-major upper triangle, k=1)
__device__ __forceinline__ int tri_idx(int i, int j) {
    return i * (2 * N_NODES - i - 1) / 2 + (j - i - 1);
}

// Single fused cooperative kernel:
//   Phase A: zero both bitmaps (uint2 per thread covers 2*262144 words exactly)
//   Phase B: one edge per thread -> device-scope atomicOr into bitmap
//   Phase C: grid-stride coalesced float4 sweep of the output
__global__ void __launch_bounds__(NTHR)
gt_fused(const float* __restrict__ Qt,
         const int* __restrict__ t_ptr,
         const int* __restrict__ et,
         const int* __restrict__ es,
         uint32_t* __restrict__ bm,
         float4* __restrict__ out) {
    cg::grid_group grid = cg::this_grid();
    const int tid = blockIdx.x * blockDim.x + threadIdx.x;

    // ---- Phase A: zero bitmaps (2 MiB total, 8 B/thread, coalesced) ----
    reinterpret_cast<uint2*>(bm)[tid] = make_uint2(0u, 0u);

    grid.sync();

    // ---- Phase B: scatter edges (tid in [0, 2*N_EDGES)) ----
    {
        const bool is_t = (tid < N_EDGES);
        const int* __restrict__ lst = is_t ? et : es;
        uint32_t* __restrict__ map = is_t ? bm : bm + BM_WORDS_PAD;
        const int e = is_t ? tid : tid - N_EDGES;
        const int i = lst[e];
        const int j = lst[N_EDGES + e];
        if (i < j) {
            const int k = tri_idx(i, j);
            atomicOr(&map[k >> 5], 1u << (k & 31));  // device-scope, idempotent
        }
    }

    grid.sync();

    // ---- Phase C: coalesced output sweep (8 grid-strides) ----
    float vals[4];
    compute_vals(Qt, t_ptr, vals);
    for (int q = tid; q < OUT_QUADS; q += NTOT) {
        const int w = q >> 3;           // 8 threads share one bitmap word
        const int sh = (q & 7) * 4;     // this thread's 4 bits
        const uint32_t wt = bm[w] >> sh;
        const uint32_t ws = bm[BM_WORDS_PAD + w] >> sh;
        float r[4];
#pragma unroll
        for (int k = 0; k < 4; ++k) {
            const bool bt = (wt >> k) & 1u;
            const bool bs = (ws >> k) & 1u;
            r[k] = bs ? (bt ? vals[3] : vals[2]) : (bt ? vals[1] : vals[0]);
        }
        out[q] = make_float4(r[0], r[1], r[2], r[3]);
    }
}

extern "C" void kernel_launch(void* const* d_in, const int* in_sizes, int n_in,
                              void* d_out, int out_size, void* d_ws, size_t ws_size,
                              hipStream_t stream) {
    const float* Qt = (const float*)d_in[0];
    const int* et = (const int*)d_in[1];
    const int* es = (const int*)d_in[2];
    const int* t_ptr = (const int*)d_in[3];
    float4* out = (float4*)d_out;
    uint32_t* bm = (uint32_t*)d_ws;  // [2][BM_WORDS_PAD] words = 2 MiB

    void* args[] = {(void*)&Qt, (void*)&t_ptr, (void*)&et, (void*)&es,
                    (void*)&bm, (void*)&out};
    hipLaunchCooperativeKernel((void*)gt_fused, dim3(NBLK), dim3(NTHR), args, 0,
                               stream);
}

// Round 3
// 81.514 us; speedup vs baseline: 3.0512x; 3.0512x over previous
//
#include <hip/hip_runtime.h>
#include <cstdint>

#define N_NODES 4096
#define N_EDGES 131072
// out_size = N*(N-1)/2 = 8386560 floats; divisible by 4 -> 2096640 uint4
#define OUT_QUADS (N_NODES * (N_NODES - 1) / 2 / 4)

// Compute the 4 candidate values exactly like the reference (l * p / e),
// then force LSB tags: index 0 -> LSB 0, 1 -> LSB 1, 2 -> LSB 0, 3 -> LSB 1.
__device__ __forceinline__ void compute_vals(const float* __restrict__ Qt,
                                             const int* __restrict__ t_ptr,
                                             float* vals) {
    const int t = t_ptr[0];
    const float l0 = Qt[2], l1 = Qt[3];                       // Qt[0][1][bt]
    const float p0 = Qt[(t - 1) * 4 + 1], p1 = Qt[(t - 1) * 4 + 3];  // Qt[t-1][bs][1]
    const float e00 = Qt[t * 4 + 0], e01 = Qt[t * 4 + 1];
    const float e10 = Qt[t * 4 + 2], e11 = Qt[t * 4 + 3];
    float v0 = l0 * p0 / e00;  // bs=0, bt=0
    float v1 = l1 * p0 / e01;  // bs=0, bt=1
    float v2 = l0 * p1 / e10;  // bs=1, bt=0
    float v3 = l1 * p1 / e11;  // bs=1, bt=1
    uint32_t u0 = __float_as_uint(v0) & ~1u;
    uint32_t u1 = __float_as_uint(v1) |  1u;
    uint32_t u2 = __float_as_uint(v2) & ~1u;
    uint32_t u3 = __float_as_uint(v3) |  1u;
    vals[0] = __uint_as_float(u0);
    vals[1] = __uint_as_float(u1);
    vals[2] = __uint_as_float(u2);
    vals[3] = __uint_as_float(u3);
}

// triangle-linear index for i<j
__device__ __forceinline__ int tri_idx(int i, int j) {
    return i * (2 * N_NODES - i - 1) / 2 + (j - i - 1);
}

// Pass 1: fill entire output with vals[0] (LSB=0). Fully coalesced uint4.
__global__ void gt_fill_default(const float* __restrict__ Qt,
                                const int* __restrict__ t_ptr,
                                float4* __restrict__ out) {
    float vals[4];
    compute_vals(Qt, t_ptr, vals);
    const float4 v = make_float4(vals[0], vals[0], vals[0], vals[0]);
    int idx = blockIdx.x * blockDim.x + threadIdx.x;  // exactly OUT_QUADS threads
    out[idx] = v;
}

// Pass 2: mark x_t edges (i<j) with vals[1] (LSB=1 tag). Plain stores.
__global__ void gt_scatter_t(const float* __restrict__ Qt,
                             const int* __restrict__ t_ptr,
                             const int* __restrict__ et,
                             float* __restrict__ out) {
    float vals[4];
    compute_vals(Qt, t_ptr, vals);
    int e = blockIdx.x * blockDim.x + threadIdx.x;
    int i = et[e];
    int j = et[N_EDGES + e];
    if (i < j) out[tri_idx(i, j)] = vals[1];
}

// Pass 3: x_start edges (i<j): read tag LSB, select vals[3] (tag kept 1) or
// vals[2] (tag kept 0). Idempotent under duplicate-edge races.
__global__ void gt_scatter_s(const float* __restrict__ Qt,
                             const int* __restrict__ t_ptr,
                             const int* __restrict__ es,
                             float* __restrict__ out) {
    float vals[4];
    compute_vals(Qt, t_ptr, vals);
    int e = blockIdx.x * blockDim.x + threadIdx.x;
    int i = es[e];
    int j = es[N_EDGES + e];
    if (i < j) {
        int idx = tri_idx(i, j);
        uint32_t cur = __float_as_uint(out[idx]);
        out[idx] = (cur & 1u) ? vals[3] : vals[2];
    }
}

extern "C" void kernel_launch(void* const* d_in, const int* in_sizes, int n_in,
                              void* d_out, int out_size, void* d_ws, size_t ws_size,
                              hipStream_t stream) {
    const float* Qt = (const float*)d_in[0];
    const int* et = (const int*)d_in[1];
    const int* es = (const int*)d_in[2];
    const int* t_ptr = (const int*)d_in[3];
    float* out = (float*)d_out;

    gt_fill_default<<<OUT_QUADS / 256, 256, 0, stream>>>(Qt, t_ptr, (float4*)out);
    gt_scatter_t<<<N_EDGES / 256, 256, 0, stream>>>(Qt, t_ptr, et, out);
    gt_scatter_s<<<N_EDGES / 256, 256, 0, stream>>>(Qt, t_ptr, es, out);
}